// Round 1
// 1652.835 us; speedup vs baseline: 1.1197x; 1.1197x over previous
//
#include <hip/hip_runtime.h>

#define L_ 6
#define H_ 8
#define C_ 512
#define V_ 32000
#define B_ 2
#define T_ 4096
#define Q_ 256
#define N_ 64
#define NC_ 16
#define M_ 8192   // B*T

typedef unsigned short u16;
typedef __attribute__((ext_vector_type(8))) short bf16x8;
typedef __attribute__((ext_vector_type(4))) float f32x4;

__device__ __forceinline__ float bf2f(u16 u){
  return __uint_as_float(((unsigned int)u) << 16);
}
__device__ __forceinline__ u16 f2bf(float f){
  unsigned int x = __float_as_uint(f);
  return (u16)((x + 0x7fffu + ((x >> 16) & 1u)) >> 16);
}

__device__ __forceinline__ void gl_lds16(const u16* g, u16* l){
  __builtin_amdgcn_global_load_lds((const __attribute__((address_space(1))) void*)g,
                                   (__attribute__((address_space(3))) void*)l, 16, 0, 0);
}

// ---------------- dtype detection: bf16 weights never have |x|>=2 ----------------
__global__ __launch_bounds__(256) void detect_kernel(const void* __restrict__ probe,
                                                     int* __restrict__ flag){
  __shared__ int cnt;
  if (threadIdx.x == 0) cnt = 0;
  __syncthreads();
  const u16* p = (const u16*)probe;
  int c = 0;
  for (int i = threadIdx.x; i < 2048; i += 256){
    int e = (p[i] >> 7) & 0xFF;
    if (e >= 128) c++;
  }
  atomicAdd(&cnt, c);
  __syncthreads();
  if (threadIdx.x == 0) *flag = (cnt > 32) ? 1 : 0;  // 1 = inputs are fp32
}

// ---------------- canonicalize all inputs to bf16 in ONE launch ----------------
struct CvtTab { const void* s[23]; u16* d[23]; int n[23]; };

__global__ __launch_bounds__(256) void convert_all(CvtTab t, const int* __restrict__ flag){
  const bool f32 = (*flag != 0);
  const int stride = gridDim.x * 256;
  #pragma unroll 1
  for (int i = 0; i < 23; i++){
    const int n8 = t.n[i] >> 3;             // all sizes are multiples of 8
    const float4* sf = (const float4*)t.s[i];
    const uint4*  sh = (const uint4*)t.s[i];
    uint4* d = (uint4*)t.d[i];
    for (int j = blockIdx.x*256 + threadIdx.x; j < n8; j += stride){
      uint4 r;
      if (f32){
        float4 a = sf[2*j], b = sf[2*j+1];
        r.x = (unsigned)f2bf(a.x) | ((unsigned)f2bf(a.y) << 16);
        r.y = (unsigned)f2bf(a.z) | ((unsigned)f2bf(a.w) << 16);
        r.z = (unsigned)f2bf(b.x) | ((unsigned)f2bf(b.y) << 16);
        r.w = (unsigned)f2bf(b.z) | ((unsigned)f2bf(b.w) << 16);
      } else r = sh[j];
      d[j] = r;
    }
  }
}

// ---------------- embedding: x = wte[idx] + wpe ----------------
__global__ __launch_bounds__(256) void embed_kernel(const int* __restrict__ idx,
    const u16* __restrict__ wte, const u16* __restrict__ wpe, float* __restrict__ x){
  int row = blockIdx.x;                 // b*T + t
  int t = row & (T_-1);
  int tok = idx[row];
  const u16* we = wte + (size_t)tok * C_;
  const u16* wp = wpe + (size_t)t * C_;
  float* xo = x + (size_t)row * C_;
  int c = threadIdx.x;
  xo[c]     = bf2f(we[c])     + bf2f(wp[c]);
  xo[c+256] = bf2f(we[c+256]) + bf2f(wp[c+256]);
}

// ---------------- fused LN + time-mix token shift (recomputes LN of row t-1) ----------------
__global__ __launch_bounds__(256) void ln_tmix_kernel(const float* __restrict__ x,
    const u16* __restrict__ w,
    const u16* __restrict__ mk, const u16* __restrict__ mv,
    const u16* __restrict__ mr, const u16* __restrict__ mg,
    u16* __restrict__ xk, u16* __restrict__ xv, u16* __restrict__ xr, u16* __restrict__ xg){
  int row = blockIdx.x; int t = row & (T_-1);
  size_t off = (size_t)row*C_;
  const float* cur = x + off;
  int c = threadIdx.x;
  float v0 = cur[c], v1 = cur[c+256];
  float p0 = 0.f, p1 = 0.f;
  if (t){ p0 = cur[c - C_]; p1 = cur[c+256 - C_]; }
  float s = v0+v1, ss = v0*v0+v1*v1;
  float sp = p0+p1, ssp = p0*p0+p1*p1;
  int lane = c & 63, wid = c >> 6;
  #pragma unroll
  for (int o=32;o>0;o>>=1){
    s  += __shfl_down(s,o,64);  ss  += __shfl_down(ss,o,64);
    sp += __shfl_down(sp,o,64); ssp += __shfl_down(ssp,o,64);
  }
  __shared__ float r1[4], r2[4], r3[4], r4[4];
  if (lane==0){ r1[wid]=s; r2[wid]=ss; r3[wid]=sp; r4[wid]=ssp; }
  __syncthreads();
  if (c==0){
    float a =r1[0]+r1[1]+r1[2]+r1[3], bq=r2[0]+r2[1]+r2[2]+r2[3];
    float ap=r3[0]+r3[1]+r3[2]+r3[3], bp=r4[0]+r4[1]+r4[2]+r4[3];
    float mu  = a *(1.f/C_); float var  = bq*(1.f/C_) - mu*mu;
    float mup = ap*(1.f/C_); float varp = bp*(1.f/C_) - mup*mup;
    r1[0]=mu;  r2[0]=rsqrtf(fmaxf(var ,0.f)+1e-5f);
    r3[0]=mup; r4[0]=rsqrtf(fmaxf(varp,0.f)+1e-5f);
  }
  __syncthreads();
  float mu=r1[0], inv=r2[0], mup=r3[0], invp=r4[0];
  #pragma unroll
  for (int p=0;p<2;p++){
    int cc = c + p*256;
    float wc = bf2f(w[cc]);
    float xc = ((p?v1:v0)-mu)*inv*wc;
    float xp = t ? ((p?p1:p0)-mup)*invp*wc : 0.f;
    float xx = xp - xc;
    xk[off+cc] = f2bf(xc + xx*bf2f(mk[cc]));
    xv[off+cc] = f2bf(xc + xx*bf2f(mv[cc]));
    xr[off+cc] = f2bf(xc + xx*bf2f(mr[cc]));
    xg[off+cc] = f2bf(xc + xx*bf2f(mg[cc]));
  }
}

// ---------------- fused LN + channel-mix token shift ----------------
__global__ __launch_bounds__(256) void ln_cmix_kernel(const float* __restrict__ x,
    const u16* __restrict__ w,
    const u16* __restrict__ mk, const u16* __restrict__ mr,
    u16* __restrict__ xk, u16* __restrict__ xr){
  int row = blockIdx.x; int t = row & (T_-1);
  size_t off = (size_t)row*C_;
  const float* cur = x + off;
  int c = threadIdx.x;
  float v0 = cur[c], v1 = cur[c+256];
  float p0 = 0.f, p1 = 0.f;
  if (t){ p0 = cur[c - C_]; p1 = cur[c+256 - C_]; }
  float s = v0+v1, ss = v0*v0+v1*v1;
  float sp = p0+p1, ssp = p0*p0+p1*p1;
  int lane = c & 63, wid = c >> 6;
  #pragma unroll
  for (int o=32;o>0;o>>=1){
    s  += __shfl_down(s,o,64);  ss  += __shfl_down(ss,o,64);
    sp += __shfl_down(sp,o,64); ssp += __shfl_down(ssp,o,64);
  }
  __shared__ float r1[4], r2[4], r3[4], r4[4];
  if (lane==0){ r1[wid]=s; r2[wid]=ss; r3[wid]=sp; r4[wid]=ssp; }
  __syncthreads();
  if (c==0){
    float a =r1[0]+r1[1]+r1[2]+r1[3], bq=r2[0]+r2[1]+r2[2]+r2[3];
    float ap=r3[0]+r3[1]+r3[2]+r3[3], bp=r4[0]+r4[1]+r4[2]+r4[3];
    float mu  = a *(1.f/C_); float var  = bq*(1.f/C_) - mu*mu;
    float mup = ap*(1.f/C_); float varp = bp*(1.f/C_) - mup*mup;
    r1[0]=mu;  r2[0]=rsqrtf(fmaxf(var ,0.f)+1e-5f);
    r3[0]=mup; r4[0]=rsqrtf(fmaxf(varp,0.f)+1e-5f);
  }
  __syncthreads();
  float mu=r1[0], inv=r2[0], mup=r3[0], invp=r4[0];
  #pragma unroll
  for (int p=0;p<2;p++){
    int cc = c + p*256;
    float wc = bf2f(w[cc]);
    float xc = ((p?v1:v0)-mu)*inv*wc;
    float xp = t ? ((p?p1:p0)-mup)*invp*wc : 0.f;
    float xx = xp - xc;
    xk[off+cc] = f2bf(xc + xx*bf2f(mk[cc]));
    xr[off+cc] = f2bf(xc + xx*bf2f(mr[cc]));
  }
}

// ---------------- final LN for last position only ----------------
__global__ __launch_bounds__(256) void lnf_last(const float* __restrict__ x,
    const u16* __restrict__ w, float* __restrict__ xf){
  int b = blockIdx.x;
  const float* xr = x + ((size_t)b*T_ + (T_-1))*C_;
  int c = threadIdx.x;
  float v0 = xr[c], v1 = xr[c+256];
  float s = v0+v1, ss = v0*v0+v1*v1;
  int lane = c & 63, wid = c >> 6;
  #pragma unroll
  for (int o=32;o>0;o>>=1){ s += __shfl_down(s,o,64); ss += __shfl_down(ss,o,64); }
  __shared__ float r1[4], r2[4];
  if (lane==0){ r1[wid]=s; r2[wid]=ss; }
  __syncthreads();
  if (c==0){
    float a=r1[0]+r1[1]+r1[2]+r1[3], bq=r2[0]+r2[1]+r2[2]+r2[3];
    float mu = a*(1.f/C_);
    float var = bq*(1.f/C_) - mu*mu;
    r1[0]=mu; r2[0]=rsqrtf(fmaxf(var,0.f)+1e-5f);
  }
  __syncthreads();
  float mu=r1[0], inv=r2[0];
  xf[b*C_+c]     = (v0-mu)*inv*bf2f(w[c]);
  xf[b*C_+c+256] = (v1-mu)*inv*bf2f(w[c+256]);
}

// ================= MFMA GEMM: Y[M,N] = X[M,K] @ W[N,K]^T =================
// Tile 128(M)x64(N), BK=64, 24KB LDS. 4 waves; wave wv computes rows
// [wv*32, wv*32+32) x all 64 cols (2x4 fragments of 16x16).
#define ACT_F32 0
#define ACT_RELU2_BF16 1
#define ACT_ADD_F32 2
#define ACT_BF16 3
#define ACT_CMIX 4   // Yf += v * sigmoid(Aux)

template<int ACT>
__device__ __forceinline__ void gemm_mfma_body(const u16* __restrict__ X, const u16* __restrict__ W,
    float* __restrict__ Yf, u16* __restrict__ Yb, const float* __restrict__ Aux,
    int Ndim, int Kdim, int bm, int bn){
  __shared__ __align__(16) u16 Al[128*64];   // 16 KB
  __shared__ __align__(16) u16 Bl[64*64];    // 8 KB
  const int tid = threadIdx.x;
  const int wv = tid >> 6, ln = tid & 63;
  const int m16 = ln & 15, q = ln >> 4;

  f32x4 acc[2][4];
  #pragma unroll
  for (int i=0;i<2;i++)
    #pragma unroll
    for (int j=0;j<4;j++) acc[i][j] = f32x4{0.f,0.f,0.f,0.f};

  const int r0 = wv*8 + (ln >> 3);
  const int c0 = (ln & 7)*8;
  const u16* ga = X + (size_t)(bm + r0)*Kdim + c0;
  const u16* gb = W + (size_t)(bn + r0)*Kdim + c0;
  u16* la = Al + r0*64 + c0;
  u16* lb = Bl + r0*64 + c0;

  for (int k0=0; k0<Kdim; k0+=64){
    #pragma unroll
    for (int s=0;s<4;s++)
      gl_lds16(ga + (size_t)(s*32)*Kdim + k0, la + s*2048);
    #pragma unroll
    for (int s=0;s<2;s++)
      gl_lds16(gb + (size_t)(s*32)*Kdim + k0, lb + s*2048);
    __syncthreads();
    #pragma unroll
    for (int kh=0; kh<2; kh++){
      bf16x8 af[2], bfr[4];
      #pragma unroll
      for (int i=0;i<2;i++) af[i]  = *(const bf16x8*)(Al + (wv*32 + i*16 + m16)*64 + kh*32 + q*8);
      #pragma unroll
      for (int j=0;j<4;j++) bfr[j] = *(const bf16x8*)(Bl + (j*16 + m16)*64 + kh*32 + q*8);
      #pragma unroll
      for (int i=0;i<2;i++)
        #pragma unroll
        for (int j=0;j<4;j++)
          acc[i][j] = __builtin_amdgcn_mfma_f32_16x16x32_bf16(af[i], bfr[j], acc[i][j], 0, 0, 0);
    }
    __syncthreads();
  }

  // epilogue: C/D layout col=lane&15, row=quad*4+reg
  #pragma unroll
  for (int i=0;i<2;i++){
    int row = bm + wv*32 + i*16 + q*4;
    #pragma unroll
    for (int j=0;j<4;j++){
      int col = bn + j*16 + m16;
      #pragma unroll
      for (int r=0;r<4;r++){
        size_t off = (size_t)(row + r)*Ndim + col;
        float v = acc[i][j][r];
        if (ACT==ACT_F32) Yf[off] = v;
        else if (ACT==ACT_RELU2_BF16){ float rr = v>0.f ? v : 0.f; Yb[off] = f2bf(rr*rr); }
        else if (ACT==ACT_BF16) Yb[off] = f2bf(v);
        else if (ACT==ACT_CMIX){ float rr = Aux[off]; Yf[off] += v/(1.f+expf(-rr)); }
        else Yf[off] += v;
      }
    }
  }
}

template<int ACT>
__global__ __launch_bounds__(256,4) void gemm_mfma(const u16* __restrict__ X, const u16* __restrict__ W,
    float* __restrict__ Yf, u16* __restrict__ Yb, int Ndim, int Kdim){
  gemm_mfma_body<ACT>(X, W, Yf, Yb, nullptr, Ndim, Kdim, blockIdx.x*128, blockIdx.y*64);
}

// fused r/k/v/g projections
__global__ __launch_bounds__(256,4) void gemm4_mfma(const u16* __restrict__ Abase,
    const u16* __restrict__ W0, const u16* __restrict__ W1,
    const u16* __restrict__ W2, const u16* __restrict__ W3,
    u16* __restrict__ Obase){
  const size_t MC = (size_t)M_*C_;
  const int z = blockIdx.z;
  const u16* X; const u16* W;
  switch (z){
    case 0:  X = Abase + 2*MC; W = W0; break;   // Rb <- MR @ Wr
    case 1:  X = Abase;        W = W1; break;   // Kb <- MK @ Wk
    case 2:  X = Abase + 1*MC; W = W2; break;   // Vb <- MV @ Wv
    default: X = Abase + 3*MC; W = W3; break;   // Gb <- MG @ Wg
  }
  gemm_mfma_body<ACT_BF16>(X, W, nullptr, Obase + (size_t)z*MC, nullptr, C_, C_,
                           blockIdx.x*128, blockIdx.y*64);
}

// fused cmix key (relu^2 -> H1 bf16) + receptance (-> RR f32) GEMMs in one launch
__global__ __launch_bounds__(256,4) void gemm_ck_cr(const u16* __restrict__ MK, const u16* __restrict__ Wck,
    u16* __restrict__ H1, const u16* __restrict__ MV, const u16* __restrict__ Wcr,
    float* __restrict__ RR){
  if (blockIdx.y < 24)
    gemm_mfma_body<ACT_RELU2_BF16>(MK, Wck, nullptr, H1, nullptr, 3*C_, C_,
                                   blockIdx.x*128, blockIdx.y*64);
  else
    gemm_mfma_body<ACT_F32>(MV, Wcr, RR, nullptr, nullptr, C_, C_,
                            blockIdx.x*128, (blockIdx.y-24)*64);
}

// cmix value GEMM with fused tail: X += sigmoid(RR) * (H1 @ Wcv^T)
__global__ __launch_bounds__(256,4) void gemm_cmix(const u16* __restrict__ H1, const u16* __restrict__ Wcv,
    float* __restrict__ X, const float* __restrict__ RR){
  gemm_mfma_body<ACT_CMIX>(H1, Wcv, X, nullptr, RR, C_, 3*C_,
                           blockIdx.x*128, blockIdx.y*64);
}

// ---------------- per-(b,h) transpose: Vt[(bh)*64+n][t] = Vb[(b*T+t)*C + h*64+n] ----------------
__global__ __launch_bounds__(256) void vt_transpose(const u16* __restrict__ Vb, u16* __restrict__ Vt){
  __shared__ __align__(16) u16 tile[64*64];
  const int t0 = blockIdx.x*64, bh = blockIdx.y, b = bh>>3, h = bh&7;
  const int tid = threadIdx.x;
  #pragma unroll
  for (int it=0; it<2; ++it){
    int tl = it*32 + (tid>>3);
    int n0 = (tid&7)*8;
    uint4 v = *(const uint4*)(Vb + ((size_t)(b*T_ + t0 + tl))*C_ + h*N_ + n0);
    int col = n0 ^ (((tl>>3)&7)<<3);
    *(uint4*)&tile[tl*64 + col] = v;
  }
  __syncthreads();
  #pragma unroll
  for (int it=0; it<2; ++it){
    int nl = it*32 + (tid>>3);
    int t0l = (tid&7)*8;
    int swz = (tid&7)<<3;
    union {uint4 q; u16 h2[8];} pk;
    #pragma unroll
    for (int e=0;e<8;++e)
      pk.h2[e] = tile[(t0l+e)*64 + (nl ^ swz)];
    *(uint4*)(Vt + ((size_t)(bh*N_ + nl))*T_ + t0 + t0l) = pk.q;
  }
}

// ---------------- WKV intra-chunk, MFMA: y = ((r@k^T) * Wmat) @ v ----------------
__global__ __launch_bounds__(256) void wkv_intra_mfma(const u16* __restrict__ Rb,
    const u16* __restrict__ Kb, const u16* __restrict__ Vt,
    const u16* __restrict__ td, const u16* __restrict__ tf, float* __restrict__ y){
  __shared__ float wpow[Q_];
  __shared__ __align__(16) u16 P[4][16][72];
  const int c = blockIdx.x >> 2, ip = blockIdx.x & 3;
  const int bh = blockIdx.y, b = bh >> 3, h = bh & 7;
  const int tid = threadIdx.x, wv = tid >> 6, ln = tid & 63;
  const int m16 = ln & 15, q = ln >> 4;
  const float wdec = expf(-expf(bf2f(td[h])));
  const float uu = bf2f(tf[h]);
  wpow[tid] = powf(wdec, (float)tid);
  __syncthreads();
  const size_t base = ((size_t)b*T_ + (size_t)c*Q_)*C_ + h*N_;
  const int iw0 = ip*64 + wv*16;
  const u16* rrow = Rb + base + (size_t)(iw0 + m16)*C_;
  bf16x8 af0 = *(const bf16x8*)(rrow + q*8);
  bf16x8 af1 = *(const bf16x8*)(rrow + 32 + q*8);
  f32x4 acc[4];
  #pragma unroll
  for (int nt=0;nt<4;++nt) acc[nt] = f32x4{0.f,0.f,0.f,0.f};
  const int irow = iw0 + q*4;
  const u16* vtb = Vt + (size_t)(bh*N_)*T_ + (size_t)c*Q_;
  for (int jt=0; jt<=ip; ++jt){
    f32x4 s[4];
    #pragma unroll
    for (int j2=0;j2<4;++j2) s[j2] = f32x4{0.f,0.f,0.f,0.f};
    #pragma unroll
    for (int j2=0;j2<4;++j2){
      const u16* kr = Kb + base + (size_t)(jt*64 + j2*16 + m16)*C_;
      bf16x8 b0 = *(const bf16x8*)(kr + q*8);
      bf16x8 b1 = *(const bf16x8*)(kr + 32 + q*8);
      s[j2] = __builtin_amdgcn_mfma_f32_16x16x32_bf16(af0, b0, s[j2], 0,0,0);
      s[j2] = __builtin_amdgcn_mfma_f32_16x16x32_bf16(af1, b1, s[j2], 0,0,0);
    }
    #pragma unroll
    for (int j2=0;j2<4;++j2){
      int jc = jt*64 + j2*16 + m16;
      #pragma unroll
      for (int r=0;r<4;++r){
        int ic = irow + r;
        float w = (jc < ic) ? wpow[ic-jc-1] : ((jc==ic) ? uu : 0.f);
        P[wv][q*4+r][j2*16+m16] = f2bf(s[j2][r]*w);
      }
    }
    __asm__ volatile("s_waitcnt lgkmcnt(0)" ::: "memory");
    #pragma unroll
    for (int kp=0;kp<2;++kp){
      bf16x8 ap = *(const bf16x8*)&P[wv][m16][kp*32 + q*8];
      #pragma unroll
      for (int nt=0;nt<4;++nt){
        bf16x8 bv = *(const bf16x8*)(vtb + (size_t)(nt*16 + m16)*T_ + jt*64 + kp*32 + q*8);
        acc[nt] = __builtin_amdgcn_mfma_f32_16x16x32_bf16(ap, bv, acc[nt], 0,0,0);
      }
    }
  }
  #pragma unroll
  for (int nt=0;nt<4;++nt)
    #pragma unroll
    for (int r=0;r<4;++r)
      y[base + (size_t)(irow + r)*C_ + nt*16 + m16] = acc[nt][r];
}

// ---------------- per-chunk state contribution S_c = (k*wkv)^T @ v (VALU, f32) ----------------
__global__ __launch_bounds__(256) void wkv_state(const u16* __restrict__ Kb, const u16* __restrict__ Vb,
    const u16* __restrict__ td, float* __restrict__ S){
  __shared__ float kst[64][68];
  __shared__ float vst[64][68];
  __shared__ float wpow[Q_];
  const int c = blockIdx.x, bh = blockIdx.y, b = bh>>3, h = bh&7;
  const int tid = threadIdx.x, tx = tid&15, ty = tid>>4;
  const float wdec = expf(-expf(bf2f(td[h])));
  wpow[tid] = powf(wdec, (float)tid);
  const size_t base = ((size_t)b*T_ + (size_t)c*Q_)*C_ + h*N_;
  float acc[4][4] = {};
  for (int jt=0;jt<4;++jt){
    __syncthreads();
    {
      const int rr = tid >> 6, cc2 = tid & 63;
      const int j0 = jt*64;
      for (int it=0; it<16; ++it){
        int j = it*4 + rr;
        kst[j][cc2] = bf2f(Kb[base + (size_t)(j0+j)*C_ + cc2]);
        vst[j][cc2] = bf2f(Vb[base + (size_t)(j0+j)*C_ + cc2]);
      }
    }
    __syncthreads();
    for (int jl=0;jl<64;++jl){
      float f = wpow[Q_-1-(jt*64+jl)];
      float kv[4], vv[4];
      #pragma unroll
      for (int mm=0;mm<4;mm++) kv[mm]=kst[jl][ty*4+mm]*f;
      #pragma unroll
      for (int nn=0;nn<4;nn++) vv[nn]=vst[jl][tx*4+nn];
      #pragma unroll
      for (int mm=0;mm<4;mm++)
        #pragma unroll
        for (int nn=0;nn<4;nn++) acc[mm][nn]+=kv[mm]*vv[nn];
    }
  }
  float* Sp = S + ((size_t)bh*NC_ + c)*(N_*N_);
  #pragma unroll
  for (int mm=0;mm<4;mm++)
    #pragma unroll
    for (int nn=0;nn<4;nn++)
      Sp[(ty*4+mm)*N_ + tx*4+nn] = acc[mm][nn];
}

// ---------------- sequential prefix over chunks ----------------
__global__ __launch_bounds__(256) void wkv_prefix(float* __restrict__ S, const u16* __restrict__ td){
  const int bh = blockIdx.x, h = bh&7;
  const float wdec = expf(-expf(bf2f(td[h])));
  const float wsd = powf(wdec, (float)Q_);
  float* Sp = S + (size_t)bh*NC_*N_*N_;
  for (int e=threadIdx.x; e<N_*N_; e+=256){
    float cur = 0.f;
    for (int cc=0;cc<NC_;++cc){
      float sc = Sp[(size_t)cc*N_*N_ + e];
      Sp[(size_t)cc*N_*N_ + e] = cur;
      cur = wsd*cur + sc;
    }
  }
}

// ---------------- inter-chunk + fused GroupNorm + silu(g): out = GN(y_intra + r@S*wdec^i)*silu(g) ----------------
__global__ __launch_bounds__(256) void wkv_inter_gn(const u16* __restrict__ Rb, const float* __restrict__ S,
    const u16* __restrict__ td, const float* __restrict__ y,
    const u16* __restrict__ gnw, const u16* __restrict__ gnb, const u16* __restrict__ g,
    u16* __restrict__ out){
  __shared__ float st[64][65];
  __shared__ float rs[64][68];
  __shared__ float wpow[Q_];
  const int c = blockIdx.x>>2, ip = blockIdx.x&3;
  const int bh = blockIdx.y, b = bh>>3, h = bh&7;
  const int tid = threadIdx.x, tx = tid&15, ty = tid>>4;
  const float wdec = expf(-expf(bf2f(td[h])));
  wpow[tid] = powf(wdec, (float)tid);
  const float* Sp = S + ((size_t)bh*NC_ + c)*(N_*N_);
  for (int e=tid;e<N_*N_;e+=256) st[e>>6][e&63] = Sp[e];
  const size_t base = ((size_t)b*T_ + (size_t)c*Q_)*C_ + h*N_;
  const int i0 = ip*64;
  {
    const int rr = tid >> 6, cc2 = tid & 63;
    for (int it=0;it<16;++it){ int i=it*4+rr; rs[i][cc2]=bf2f(Rb[base+(size_t)(i0+i)*C_+cc2]); }
  }
  __syncthreads();
  float acc[4][4] = {};
  for (int kk=0;kk<N_;++kk){
    float rv[4], sv[4];
    #pragma unroll
    for (int ii=0;ii<4;ii++) rv[ii]=rs[ty*4+ii][kk];
    #pragma unroll
    for (int nn=0;nn<4;nn++) sv[nn]=st[kk][tx*4+nn];
    #pragma unroll
    for (int ii=0;ii<4;ii++)
      #pragma unroll
      for (int nn=0;nn<4;nn++) acc[ii][nn]+=rv[ii]*sv[nn];
  }
  // each row (token) is held by the 16 lanes sharing ty: 16-lane shfl reduce for GN stats
  #pragma unroll
  for (int ii=0;ii<4;ii++){
    int il = i0+ty*4+ii;
    size_t roff = base + (size_t)il*C_;
    float w = wpow[il];
    float val[4];
    float s=0.f, ss=0.f;
    #pragma unroll
    for (int nn=0;nn<4;nn++){
      float v = y[roff + tx*4+nn] + w*acc[ii][nn];
      val[nn]=v; s+=v; ss+=v*v;
    }
    #pragma unroll
    for (int o=8;o>0;o>>=1){ s+=__shfl_xor(s,o,64); ss+=__shfl_xor(ss,o,64); }
    float mu = s*(1.f/N_);
    float var = ss*(1.f/N_) - mu*mu;
    float inv = rsqrtf(fmaxf(var,0.f) + 6.4e-4f);   // GN_EPS = 1e-5*64
    #pragma unroll
    for (int nn=0;nn<4;nn++){
      int n = tx*4+nn, ci = h*N_+n;
      float gg = bf2f(g[roff+n]);
      float sil = gg/(1.f+expf(-gg));
      out[roff+n] = f2bf(((val[nn]-mu)*inv*bf2f(gnw[ci]) + bf2f(gnb[ci]))*sil);
    }
  }
}

// ---------------- logits for last position: [B,V] = xf @ wte^T ----------------
__global__ __launch_bounds__(256) void logits_kernel(const float* __restrict__ xf,
    const u16* __restrict__ wte, void* __restrict__ out, const int* __restrict__ flag){
  const int wid = threadIdx.x>>6, lane = threadIdx.x&63;
  const int gw = blockIdx.x*4 + wid;     // 0 .. B*V-1
  const int b = gw / V_, v = gw - b*V_;
  const u16* wrow = wte + (size_t)v*C_;
  const float* xr = xf + b*C_;
  union {uint4 q; u16 h[8];} uu;
  uu.q = *(const uint4*)(wrow + lane*8);
  float s = 0.f;
  #pragma unroll
  for (int j=0;j<8;j++) s += bf2f(uu.h[j])*xr[lane*8+j];
  #pragma unroll
  for (int o=32;o>0;o>>=1) s += __shfl_down(s,o,64);
  if (lane==0){
    size_t o = (size_t)b*V_ + v;
    if (*flag) ((float*)out)[o] = s;          // fp32 harness
    else       ((u16*)out)[o]   = f2bf(s);    // bf16 harness
  }
}

extern "C" void kernel_launch(void* const* d_in, const int* in_sizes, int n_in,
                              void* d_out, int out_size, void* d_ws, size_t ws_size,
                              hipStream_t stream){
  (void)out_size; (void)ws_size; (void)n_in;
  const int* idx  = (const int*)d_in[0];

  char* ws = (char*)d_ws;
  const size_t MC  = (size_t)M_*C_;
  // ---- workspace layout (bytes) ----
  size_t o = 0;
  int* flag = (int*)(ws + o);            o += 1024;
  float* X   = (float*)(ws + o);         o += MC*4;            // fp32 residual
  float* Y   = (float*)(ws + o);         o += MC*4;            // wkv intra result (f32)
  u16* MK = (u16*)(ws + o);              o += MC*2;            // also YGN
  u16* MV = (u16*)(ws + o);              o += MC*2;
  u16* MR = (u16*)(ws + o);              o += MC*2;            // also S (tmix) / RR (cmix)
  u16* MG = (u16*)(ws + o);              o += MC*2;
  u16* Rb = (u16*)(ws + o);              o += MC*2;            // H1 spans Rb..Vb
  u16* Kb = (u16*)(ws + o);              o += MC*2;
  u16* Vb = (u16*)(ws + o);              o += MC*2;
  u16* Gb = (u16*)(ws + o);              o += MC*2;
  u16* Vt = (u16*)(ws + o);              o += MC*2;            // v^T per (b,h): [BH*64, T]
  float* XF = (float*)(ws + o);          o += 65536;
  u16* pool = (u16*)(ws + o);            // canonical bf16 inputs
  u16* YGN = MK;
  float* S  = (float*)MR;    // live only during tmix phase (4 MB < 8.4 MB)
  u16* H1 = Rb;              // [M,3C] bf16, spans Rb..Vb
  float* RR = (float*)MR;    // [M,C] f32, spans MR..MG — disjoint from H1

  // ---- dtype detect + canonicalize all non-integer inputs (single launch) ----
  detect_kernel<<<1,256,0,stream>>>(d_in[12], flag);   // probe Wr
  u16* cw[24];
  CvtTab tab;
  {
    size_t poff = 0;
    for (int i=1;i<24;i++){
      cw[i] = pool + poff; poff += (size_t)in_sizes[i];
      tab.s[i-1] = d_in[i]; tab.d[i-1] = cw[i]; tab.n[i-1] = in_sizes[i];
    }
  }
  convert_all<<<2048,256,0,stream>>>(tab, flag);
  const u16* wte  = cw[1];  const u16* wpe  = cw[2];
  const u16* ln1w = cw[3];  const u16* ln2w = cw[4];  const u16* lnfw = cw[5];
  const u16* maak = cw[6];  const u16* maav = cw[7];
  const u16* maar = cw[8];  const u16* maag = cw[9];
  const u16* tdec = cw[10]; const u16* tfir = cw[11];
  const u16* Wr   = cw[12]; const u16* Wk   = cw[13]; const u16* Wv   = cw[14];
  const u16* Wg   = cw[15]; const u16* Wo   = cw[16];
  const u16* gnw  = cw[17]; const u16* gnb  = cw[18];
  const u16* cmk  = cw[19]; const u16* cmr  = cw[20];
  const u16* Wck  = cw[21]; const u16* Wcv  = cw[22]; const u16* Wcr  = cw[23];

  embed_kernel<<<M_,256,0,stream>>>(idx,wte,wpe,X);
  dim3 gsq(M_/128, C_/64);         // (64, 8)
  dim3 g4 (M_/128, C_/64, 4);      // fused projections
  dim3 gckcr(M_/128, 32);          // fused Wck (24 col-tiles) + Wcr (8 col-tiles)
  for (int l=0;l<L_;++l){
    // ---- time mix ----
    ln_tmix_kernel<<<M_,256,0,stream>>>(X, ln1w+l*C_, maak+l*C_, maav+l*C_, maar+l*C_,
                                        maag+l*C_, MK,MV,MR,MG);
    gemm4_mfma<<<g4,256,0,stream>>>(MK, Wr+(size_t)l*C_*C_, Wk+(size_t)l*C_*C_,
                                    Wv+(size_t)l*C_*C_, Wg+(size_t)l*C_*C_, Rb);
    vt_transpose<<<dim3(T_/64, B_*H_),256,0,stream>>>(Vb, Vt);
    wkv_intra_mfma<<<dim3(NC_*4, B_*H_),256,0,stream>>>(Rb,Kb,Vt, tdec+l*H_, tfir+l*H_, Y);
    wkv_state<<<dim3(NC_,   B_*H_),256,0,stream>>>(Kb,Vb, tdec+l*H_, S);
    wkv_prefix<<<B_*H_,256,0,stream>>>(S, tdec+l*H_);
    wkv_inter_gn<<<dim3(NC_*4, B_*H_),256,0,stream>>>(Rb, S, tdec+l*H_, Y,
                                                      gnw+l*C_, gnb+l*C_, Gb, YGN);
    gemm_mfma<ACT_ADD_F32><<<gsq,256,0,stream>>>(YGN, Wo+(size_t)l*C_*C_, X, nullptr, C_, C_);
    // ---- channel mix ----
    ln_cmix_kernel<<<M_,256,0,stream>>>(X, ln2w+l*C_, cmk+l*C_, cmr+l*C_, MK, MV);
    gemm_ck_cr<<<gckcr,256,0,stream>>>(MK, Wck+(size_t)l*3*C_*C_, H1,
                                       MV, Wcr+(size_t)l*C_*C_, RR);
    gemm_cmix<<<gsq,256,0,stream>>>(H1, Wcv+(size_t)l*C_*3*C_, X, RR);
  }
  lnf_last<<<B_,256,0,stream>>>(X, lnfw, XF);
  logits_kernel<<<(B_*V_)/4,256,0,stream>>>(XF, wte, d_out, flag);
}